// Round 3
// baseline (170.419 us; speedup 1.0000x reference)
//
#include <hip/hip_runtime.h>
#include <hip/hip_bf16.h>

#define T 128
#define C 20
#define KQ 100
#define NT 512
#define SCALE 0.08838834764831845f   // 1/sqrt(128)
#define K2E   0.12751744f            // SCALE * log2(e)
#define LOG2E 1.4426950408889634f
#define LDS8 136   // fp8 row stride (bytes): 34 dw == 2 mod 32 -> all accesses <=2-way (free)

typedef float  f32x4  __attribute__((ext_vector_type(4)));
typedef short  bf16x8 __attribute__((ext_vector_type(8)));
typedef unsigned int uint32;

__device__ __forceinline__ short f2bf(float f) {
    unsigned u = __builtin_bit_cast(unsigned, f);
    unsigned r = (u + 0x7FFFu + ((u >> 16) & 1u)) >> 16;   // RNE
    return (short)r;
}
__device__ __forceinline__ uint32 pk2(float a, float b) {  // v_cvt_pk_bf16_f32
    __hip_bfloat162 h = __float22bfloat162_rn(float2{a, b});
    uint32 r;
    __builtin_memcpy(&r, &h, 4);
    return r;
}
__device__ __forceinline__ int pkfp8x4(float a, float b, float c, float d) {
    int r = __builtin_amdgcn_cvt_pk_fp8_f32(a, b, 0, false);   // bytes 0,1
    r = __builtin_amdgcn_cvt_pk_fp8_f32(c, d, r, true);        // bytes 2,3
    return r;
}
__device__ __forceinline__ unsigned char fp8_1(float a) {
    return (unsigned char)(__builtin_amdgcn_cvt_pk_fp8_f32(a, 0.f, 0, false) & 0xff);
}

// ---- prep: weights -> bf16 A-fragment tiles in d_ws, BIAS FOLDED at c==20 ----
// wAll = 16 tiles x [16 ch][32 c] bf16 (k:0..6, q:7..13, v:14..15).
// Row c=20 of each tile holds the bias (x fragment supplies 1.0 there).
__global__ void prep(const float* __restrict__ Wk, const float* __restrict__ bk,
                     const float* __restrict__ Wq, const float* __restrict__ bq,
                     const float* __restrict__ Wv, const float* __restrict__ bv,
                     short* __restrict__ wkT, short* __restrict__ wqT,
                     short* __restrict__ wvT)
{
    const int t = blockIdx.x * blockDim.x + threadIdx.x;
    if (t < 112 * 32) {
        const int n = t >> 5, c = t & 31;
        float vk = 0.f, vq = 0.f;
        if (n < KQ) {
            if (c < C)       { vk = Wk[c * KQ + n]; vq = Wq[c * KQ + n]; }
            else if (c == C) { vk = bk[n];          vq = bq[n]; }
        }
        wkT[t] = f2bf(vk);
        wqT[t] = f2bf(vq);
        if (t < 32 * 32) {
            const int n2 = t >> 5, c2 = t & 31;
            float vv = 0.f;
            if (n2 < C) {
                if (c2 < C)       vv = Wv[c2 * C + n2];
                else if (c2 == C) vv = bv[n2];
            }
            wvT[t] = f2bf(vv);
        }
    }
}

// R2 theory: rocprof showed VGPR_Count=32 (launch_bounds(512,8) caps budget
// at 64/wave -> acc[8] forced into AGPRs, accvgpr-move storm explains
// VALUBusy=69% at only ~1600 source-level issue cycles/wave) while actual
// occupancy was ~73% (3 blocks/CU) anyway. Relax to (512,6): same residency,
// ~80 regs/wave, accumulators stay in VGPRs. Also fold log2e into all exp
// constants (exp2f: one v_mul less per transcendental, ~96/thread).
__global__ __launch_bounds__(NT, 6) void sa_fused(
    const float* __restrict__ x,
    const short* __restrict__ wAll,
    float* __restrict__ y)
{
    __shared__ __align__(16) unsigned char kp8[T * LDS8];   // k fp8 [i][d] -> later 64*P [i][j]
    __shared__ __align__(16) unsigned char q8 [T * LDS8];   // q fp8 [j][d]
    __shared__ __align__(16) unsigned char vT8[32 * LDS8];  // v^T fp8 [dd][pos] (rows 20..31 = 0)

    const int tid  = threadIdx.x;
    const int lane = tid & 63;
    const int w    = __builtin_amdgcn_readfirstlane(tid >> 6);
    const int quad = lane >> 4;
    const int l16  = lane & 15;
    const int b    = blockIdx.x;
    const float* xb = x + (size_t)b * (T * C);

    // ---- issue x global loads FIRST (latency overlaps the LDS zero-pad) ----
    const float* xr = xb + (w * 16 + l16) * C;
    float4 f0, f1;
    f0 = (float4){0.f, 0.f, 0.f, 0.f};
    f1 = (float4){0.f, 0.f, 0.f, 0.f};
    if (quad < 2) {
        f0 = *(const float4*)(xr + quad * 8);
        f1 = *(const float4*)(xr + quad * 8 + 4);
    } else if (quad == 2) {
        f0 = *(const float4*)(xr + 16);
    }

    // ---- zero pad cols 112..127 of kp8/q8 (d-tail read by score K-loop) ----
    if (tid < T) {
        const uint2 z = {0u, 0u};
        *(uint2*)&kp8[tid * LDS8 + 112] = z;
        *(uint2*)&kp8[tid * LDS8 + 120] = z;
        *(uint2*)&q8 [tid * LDS8 + 112] = z;
        *(uint2*)&q8 [tid * LDS8 + 120] = z;
    }

    // ---- x fragment (built once): A[m=l16][k=quad*8+u] == B[k][n=l16];
    //      c pad 20->32, with c=20 element = 1.0 (bias row multiplier) ----
    bf16x8 xf;
    {
        uint32 p0 = 0, p1 = 0, p2 = 0, p3 = 0;
        if (quad < 2) {
            p0 = pk2(f0.x, f0.y); p1 = pk2(f0.z, f0.w);
            p2 = pk2(f1.x, f1.y); p3 = pk2(f1.z, f1.w);
        } else if (quad == 2) {
            p0 = pk2(f0.x, f0.y); p1 = pk2(f0.z, f0.w);
            p2 = pk2(1.f, 0.f);                       // c=20 -> 1.0 (bias row)
        }
        uint4 u4; u4.x = p0; u4.y = p1; u4.z = p2; u4.w = p3;
        xf = __builtin_bit_cast(bf16x8, u4);
    }

    // ---- projections (bf16 MFMA): wave w owns i-tile w. Weight fragments
    //      preloaded in batches of 4 (16 VGPRs) so loads pipeline. ----
    #pragma unroll
    for (int grp = 0; grp < 4; ++grp) {
        bf16x8 wfr[4];
        #pragma unroll
        for (int t = 0; t < 4; ++t)
            wfr[t] = *(const bf16x8*)(wAll + ((grp * 4 + t) * 16 + l16) * 32 + quad * 8);
        #pragma unroll
        for (int s = 0; s < 4; ++s) {
            const int tt = grp * 4 + s;
            const f32x4 cc = __builtin_amdgcn_mfma_f32_16x16x32_bf16(
                wfr[s], xf, (f32x4){0.f, 0.f, 0.f, 0.f}, 0, 0, 0);
            if (tt < 14) {                                        // k or q: ELU -> fp8 b32 write
                float e[4];
                #pragma unroll
                for (int r = 0; r < 4; ++r) {
                    const float z = cc[r];
                    e[r] = z > 0.f ? z : (exp2f(z * LOG2E) - 1.f);
                }
                unsigned char* dst = (tt < 7)
                    ? &kp8[(w * 16 + l16) * LDS8 + tt * 16 + quad * 4]
                    : &q8 [(w * 16 + l16) * LDS8 + (tt - 7) * 16 + quad * 4];
                *(int*)dst = pkfp8x4(e[0], e[1], e[2], e[3]);
            } else {                                              // v: tanh -> vT scatter (b8)
                #pragma unroll
                for (int r = 0; r < 4; ++r) {
                    const float e2 = exp2f(cc[r] * (2.f * LOG2E));
                    vT8[((tt - 14) * 16 + quad * 4 + r) * LDS8 + w * 16 + l16]
                        = fp8_1(1.f - 2.f / (e2 + 1.f));
                }
            }
        }
    }
    __syncthreads();

    // ---- scores TRANSPOSED (fp8): S^T = q.k^T. A = q rows j (m-tile w), B = k (n=i). ----
    f32x4 acc[8];
    #pragma unroll
    for (int nt = 0; nt < 8; ++nt) acc[nt] = (f32x4){0.f, 0.f, 0.f, 0.f};
    __builtin_amdgcn_s_setprio(1);
    #pragma unroll
    for (int ks = 0; ks < 4; ++ks) {
        const long a = *(const long*)&q8[(w * 16 + l16) * LDS8 + ks * 32 + quad * 8];
        #pragma unroll
        for (int nt = 0; nt < 8; ++nt) {
            const long bk8 = *(const long*)&kp8[(nt * 16 + l16) * LDS8 + ks * 32 + quad * 8];
            acc[nt] = __builtin_amdgcn_mfma_f32_16x16x32_fp8_fp8(a, bk8, acc[nt], 0, 0, 0);
        }
    }
    __builtin_amdgcn_s_setprio(0);

    // ---- softmax over i (axis=1), in registers ----
    // Thread holds (j = w*16+quad*4+r, i = nt*16+l16). Sum over i = nt-sum + l16 butterfly.
    float ssum[4] = {0.f, 0.f, 0.f, 0.f};
    #pragma unroll
    for (int nt = 0; nt < 8; ++nt)
        #pragma unroll
        for (int r = 0; r < 4; ++r) {
            const float e = exp2f(acc[nt][r] * K2E);
            acc[nt][r] = e;
            ssum[r] += e;
        }
    #pragma unroll
    for (int r = 0; r < 4; ++r) {
        float s = ssum[r];
        s += __shfl_xor(s, 1); s += __shfl_xor(s, 2);
        s += __shfl_xor(s, 4); s += __shfl_xor(s, 8);
        ssum[r] = 64.f / s;                                       // 64*linv[j] (fp8 range lift)
    }
    __syncthreads();                                              // all score reads of kp8/q8 done

    // ---- write 64*P[i][j] fp8 (b32: 4 consecutive j per thread) over k ----
    #pragma unroll
    for (int nt = 0; nt < 8; ++nt) {
        *(int*)&kp8[(nt * 16 + l16) * LDS8 + w * 16 + quad * 4]
            = pkfp8x4(acc[nt][0] * ssum[0], acc[nt][1] * ssum[1],
                      acc[nt][2] * ssum[2], acc[nt][3] * ssum[3]);
    }
    __syncthreads();

    // ---- PV (fp8): A = 64P (m-tile w, K = j = 128), B = v^T (N = 32) ----
    f32x4 yacc[2];
    yacc[0] = (f32x4){0.f, 0.f, 0.f, 0.f};
    yacc[1] = (f32x4){0.f, 0.f, 0.f, 0.f};
    __builtin_amdgcn_s_setprio(1);
    #pragma unroll
    for (int ks = 0; ks < 4; ++ks) {
        const long a = *(const long*)&kp8[(w * 16 + l16) * LDS8 + ks * 32 + quad * 8];
        #pragma unroll
        for (int nt = 0; nt < 2; ++nt) {
            const long bv8 = *(const long*)&vT8[(nt * 16 + l16) * LDS8 + ks * 32 + quad * 8];
            yacc[nt] = __builtin_amdgcn_mfma_f32_16x16x32_fp8_fp8(a, bv8, yacc[nt], 0, 0, 0);
        }
    }
    __builtin_amdgcn_s_setprio(0);

    // ---- epilogue: y = PV/64 + x (direct stores, R8-known-good) ----
    {
        float* yb = y + (size_t)b * (T * C);
        const float inv64 = 1.f / 64.f;
        #pragma unroll
        for (int r = 0; r < 4; ++r) {
            const int row  = w * 16 + quad * 4 + r;
            const int base = row * C;
            yb[base + l16] = yacc[0][r] * inv64 + xb[base + l16];
            if (l16 < 4)
                yb[base + 16 + l16] = yacc[1][r] * inv64 + xb[base + 16 + l16];
        }
    }
}

extern "C" void kernel_launch(void* const* d_in, const int* in_sizes, int n_in,
                              void* d_out, int out_size, void* d_ws, size_t ws_size,
                              hipStream_t stream) {
    const float* x  = (const float*)d_in[0];
    const float* Wk = (const float*)d_in[1];
    const float* bk = (const float*)d_in[2];
    const float* Wq = (const float*)d_in[3];
    const float* bq = (const float*)d_in[4];
    const float* Wv = (const float*)d_in[5];
    const float* bv = (const float*)d_in[6];
    float* y = (float*)d_out;

    char* ws = (char*)d_ws;
    short* wkT = (short*)ws;                 // tiles 0..6   [112][32] bf16 (bias at c=20)
    short* wqT = (short*)(ws + 7168);        // tiles 7..13  [112][32] bf16
    short* wvT = (short*)(ws + 14336);       // tiles 14..15 [32][32]  bf16

    prep<<<14, 256, 0, stream>>>(Wk, bk, Wq, bq, Wv, bv, wkT, wqT, wvT);

    const int B = in_sizes[0] / (T * C);     // 4096
    sa_fused<<<B, NT, 0, stream>>>(x, (const short*)ws, y);
}

// Round 5
// 160.402 us; speedup vs baseline: 1.0625x; 1.0625x over previous
//
#include <hip/hip_runtime.h>
#include <hip/hip_bf16.h>

#define T 128
#define C 20
#define KQ 100
#define NT 512
#define SCALE 0.08838834764831845f   // 1/sqrt(128)
#define K2E   0.12751744f            // SCALE * log2(e)
#define LOG2E 1.4426950408889634f
#define TWOL2E 2.885390081777927f    // 2*log2(e), folded into Wv/bv in prep
#define LDS8 136   // fp8 row stride (bytes): 34 dw == 2 mod 32 -> all accesses <=2-way (free)

typedef float  f32x4  __attribute__((ext_vector_type(4)));
typedef short  bf16x8 __attribute__((ext_vector_type(8)));
typedef unsigned int uint32;

// single-instruction transcendentals via PROPER builtins (hazard-modeled by
// the compiler — R4's raw inline-asm versions hit the TRANS-op wait-state
// hazard: consumer VALU read before result ready -> NaN).
__device__ __forceinline__ float exp2i(float x) { return __builtin_amdgcn_exp2f(x); }
__device__ __forceinline__ float rcpi(float x)  { return __builtin_amdgcn_rcpf(x); }

__device__ __forceinline__ short f2bf(float f) {
    unsigned u = __builtin_bit_cast(unsigned, f);
    unsigned r = (u + 0x7FFFu + ((u >> 16) & 1u)) >> 16;   // RNE
    return (short)r;
}
__device__ __forceinline__ uint32 pk2(float a, float b) {  // v_cvt_pk_bf16_f32
    __hip_bfloat162 h = __float22bfloat162_rn(float2{a, b});
    uint32 r;
    __builtin_memcpy(&r, &h, 4);
    return r;
}
__device__ __forceinline__ int pkfp8x4(float a, float b, float c, float d) {
    int r = __builtin_amdgcn_cvt_pk_fp8_f32(a, b, 0, false);   // bytes 0,1
    r = __builtin_amdgcn_cvt_pk_fp8_f32(c, d, r, true);        // bytes 2,3
    return r;
}
__device__ __forceinline__ unsigned char fp8_1(float a) {
    return (unsigned char)(__builtin_amdgcn_cvt_pk_fp8_f32(a, 0.f, 0, false) & 0xff);
}

// ---- prep: weights -> bf16 A-fragment tiles in d_ws, BIAS FOLDED at c==20 ----
// wAll = 16 tiles x [16 ch][32 c] bf16 (k:0..6, q:7..13, v:14..15).
// Row c=20 of each tile holds the bias (x fragment supplies 1.0 there).
// v weights pre-scaled by 2*log2(e) so tanh needs no input mul in-kernel.
__global__ void prep(const float* __restrict__ Wk, const float* __restrict__ bk,
                     const float* __restrict__ Wq, const float* __restrict__ bq,
                     const float* __restrict__ Wv, const float* __restrict__ bv,
                     short* __restrict__ wkT, short* __restrict__ wqT,
                     short* __restrict__ wvT)
{
    const int t = blockIdx.x * blockDim.x + threadIdx.x;
    if (t < 112 * 32) {
        const int n = t >> 5, c = t & 31;
        float vk = 0.f, vq = 0.f;
        if (n < KQ) {
            if (c < C)       { vk = Wk[c * KQ + n]; vq = Wq[c * KQ + n]; }
            else if (c == C) { vk = bk[n];          vq = bq[n]; }
        }
        wkT[t] = f2bf(vk);
        wqT[t] = f2bf(vq);
        if (t < 32 * 32) {
            const int n2 = t >> 5, c2 = t & 31;
            float vv = 0.f;
            if (n2 < C) {
                if (c2 < C)       vv = Wv[c2 * C + n2] * TWOL2E;
                else if (c2 == C) vv = bv[n2] * TWOL2E;
            }
            wvT[t] = f2bf(vv);
        }
    }
}

// R5: issue-bound kernel (VALU 69% + MFMA 18% + DS ~9% at 4 blocks/CU max
// occupancy) -> cut dynamic instruction count via intrinsics:
//   ELU  = fmed3(z, e^z-1, 0)        [exact: e^z-1 >= z for all z]
//   tanh = 1 - 2*rcp(exp2(cc)+1)     [cc pre-scaled by 2log2e in prep]
//   softmax exp = v_exp(acc*K2E); denominators via v_rcp (2^-22 rel err,
//   absorbed by fp8 quantization; R3 validated the K2E fold numerically).
// launch_bounds(512,8) — R3 showed min-waves=6 caps residency at 3 blocks/CU.
__global__ __launch_bounds__(NT, 8) void sa_fused(
    const float* __restrict__ x,
    const short* __restrict__ wAll,
    float* __restrict__ y)
{
    __shared__ __align__(16) unsigned char kp8[T * LDS8];   // k fp8 [i][d] -> later 64*P [i][j]
    __shared__ __align__(16) unsigned char q8 [T * LDS8];   // q fp8 [j][d]
    __shared__ __align__(16) unsigned char vT8[32 * LDS8];  // v^T fp8 [dd][pos] (rows 20..31 = 0)

    const int tid  = threadIdx.x;
    const int lane = tid & 63;
    const int w    = __builtin_amdgcn_readfirstlane(tid >> 6);
    const int quad = lane >> 4;
    const int l16  = lane & 15;
    const int b    = blockIdx.x;
    const float* xb = x + (size_t)b * (T * C);

    // ---- issue x global loads FIRST (latency overlaps the LDS zero-pad) ----
    const float* xr = xb + (w * 16 + l16) * C;
    float4 f0, f1;
    f0 = (float4){0.f, 0.f, 0.f, 0.f};
    f1 = (float4){0.f, 0.f, 0.f, 0.f};
    if (quad < 2) {
        f0 = *(const float4*)(xr + quad * 8);
        f1 = *(const float4*)(xr + quad * 8 + 4);
    } else if (quad == 2) {
        f0 = *(const float4*)(xr + 16);
    }

    // ---- zero pad cols 112..127 of kp8/q8 (d-tail read by score K-loop) ----
    if (tid < T) {
        const uint2 z = {0u, 0u};
        *(uint2*)&kp8[tid * LDS8 + 112] = z;
        *(uint2*)&kp8[tid * LDS8 + 120] = z;
        *(uint2*)&q8 [tid * LDS8 + 112] = z;
        *(uint2*)&q8 [tid * LDS8 + 120] = z;
    }

    // ---- x fragment (built once): A[m=l16][k=quad*8+u] == B[k][n=l16];
    //      c pad 20->32, with c=20 element = 1.0 (bias row multiplier) ----
    bf16x8 xf;
    {
        uint32 p0 = 0, p1 = 0, p2 = 0, p3 = 0;
        if (quad < 2) {
            p0 = pk2(f0.x, f0.y); p1 = pk2(f0.z, f0.w);
            p2 = pk2(f1.x, f1.y); p3 = pk2(f1.z, f1.w);
        } else if (quad == 2) {
            p0 = pk2(f0.x, f0.y); p1 = pk2(f0.z, f0.w);
            p2 = pk2(1.f, 0.f);                       // c=20 -> 1.0 (bias row)
        }
        uint4 u4; u4.x = p0; u4.y = p1; u4.z = p2; u4.w = p3;
        xf = __builtin_bit_cast(bf16x8, u4);
    }

    // ---- projections (bf16 MFMA): wave w owns i-tile w. Weight fragments
    //      preloaded in batches of 4 (16 VGPRs) so loads pipeline. ----
    #pragma unroll
    for (int grp = 0; grp < 4; ++grp) {
        bf16x8 wfr[4];
        #pragma unroll
        for (int t = 0; t < 4; ++t)
            wfr[t] = *(const bf16x8*)(wAll + ((grp * 4 + t) * 16 + l16) * 32 + quad * 8);
        #pragma unroll
        for (int s = 0; s < 4; ++s) {
            const int tt = grp * 4 + s;
            const f32x4 cc = __builtin_amdgcn_mfma_f32_16x16x32_bf16(
                wfr[s], xf, (f32x4){0.f, 0.f, 0.f, 0.f}, 0, 0, 0);
            if (tt < 14) {                                        // k or q: ELU -> fp8 b32 write
                float e[4];
                #pragma unroll
                for (int r = 0; r < 4; ++r) {
                    const float z = cc[r];
                    // ELU(z) = median(z, e^z-1, 0): e^z-1 >= z always, so
                    // z>0 -> median=z ; z<0 -> median=e^z-1.
                    e[r] = __builtin_amdgcn_fmed3f(z, exp2i(z * LOG2E) - 1.f, 0.f);
                }
                unsigned char* dst = (tt < 7)
                    ? &kp8[(w * 16 + l16) * LDS8 + tt * 16 + quad * 4]
                    : &q8 [(w * 16 + l16) * LDS8 + (tt - 7) * 16 + quad * 4];
                *(int*)dst = pkfp8x4(e[0], e[1], e[2], e[3]);
            } else {                                              // v: tanh -> vT scatter (b8)
                #pragma unroll
                for (int r = 0; r < 4; ++r) {
                    // cc already = 2*log2e*(xWv+bv) via prep pre-scale
                    const float e2 = exp2i(cc[r]);
                    vT8[((tt - 14) * 16 + quad * 4 + r) * LDS8 + w * 16 + l16]
                        = fp8_1(fmaf(-2.f, rcpi(e2 + 1.f), 1.f));
                }
            }
        }
    }
    __syncthreads();

    // ---- scores TRANSPOSED (fp8): S^T = q.k^T. A = q rows j (m-tile w), B = k (n=i). ----
    f32x4 acc[8];
    #pragma unroll
    for (int nt = 0; nt < 8; ++nt) acc[nt] = (f32x4){0.f, 0.f, 0.f, 0.f};
    __builtin_amdgcn_s_setprio(1);
    #pragma unroll
    for (int ks = 0; ks < 4; ++ks) {
        const long a = *(const long*)&q8[(w * 16 + l16) * LDS8 + ks * 32 + quad * 8];
        #pragma unroll
        for (int nt = 0; nt < 8; ++nt) {
            const long bk8 = *(const long*)&kp8[(nt * 16 + l16) * LDS8 + ks * 32 + quad * 8];
            acc[nt] = __builtin_amdgcn_mfma_f32_16x16x32_fp8_fp8(a, bk8, acc[nt], 0, 0, 0);
        }
    }
    __builtin_amdgcn_s_setprio(0);

    // ---- softmax over i (axis=1), in registers ----
    // Thread holds (j = w*16+quad*4+r, i = nt*16+l16). Sum over i = nt-sum + l16 butterfly.
    float ssum[4] = {0.f, 0.f, 0.f, 0.f};
    #pragma unroll
    for (int nt = 0; nt < 8; ++nt)
        #pragma unroll
        for (int r = 0; r < 4; ++r) {
            const float e = exp2i(acc[nt][r] * K2E);   // exp(S*SCALE), const pre-folded
            acc[nt][r] = e;
            ssum[r] += e;
        }
    #pragma unroll
    for (int r = 0; r < 4; ++r) {
        float s = ssum[r];
        s += __shfl_xor(s, 1); s += __shfl_xor(s, 2);
        s += __shfl_xor(s, 4); s += __shfl_xor(s, 8);
        ssum[r] = 64.f * rcpi(s);                                 // 64*linv[j] (fp8 range lift)
    }
    __syncthreads();                                              // all score reads of kp8/q8 done

    // ---- write 64*P[i][j] fp8 (b32: 4 consecutive j per thread) over k ----
    #pragma unroll
    for (int nt = 0; nt < 8; ++nt) {
        *(int*)&kp8[(nt * 16 + l16) * LDS8 + w * 16 + quad * 4]
            = pkfp8x4(acc[nt][0] * ssum[0], acc[nt][1] * ssum[1],
                      acc[nt][2] * ssum[2], acc[nt][3] * ssum[3]);
    }
    __syncthreads();

    // ---- PV (fp8): A = 64P (m-tile w, K = j = 128), B = v^T (N = 32) ----
    f32x4 yacc[2];
    yacc[0] = (f32x4){0.f, 0.f, 0.f, 0.f};
    yacc[1] = (f32x4){0.f, 0.f, 0.f, 0.f};
    __builtin_amdgcn_s_setprio(1);
    #pragma unroll
    for (int ks = 0; ks < 4; ++ks) {
        const long a = *(const long*)&kp8[(w * 16 + l16) * LDS8 + ks * 32 + quad * 8];
        #pragma unroll
        for (int nt = 0; nt < 2; ++nt) {
            const long bv8 = *(const long*)&vT8[(nt * 16 + l16) * LDS8 + ks * 32 + quad * 8];
            yacc[nt] = __builtin_amdgcn_mfma_f32_16x16x32_fp8_fp8(a, bv8, yacc[nt], 0, 0, 0);
        }
    }
    __builtin_amdgcn_s_setprio(0);

    // ---- epilogue: y = PV/64 + x (direct stores, R8-known-good) ----
    {
        float* yb = y + (size_t)b * (T * C);
        const float inv64 = 1.f / 64.f;
        #pragma unroll
        for (int r = 0; r < 4; ++r) {
            const int row  = w * 16 + quad * 4 + r;
            const int base = row * C;
            yb[base + l16] = yacc[0][r] * inv64 + xb[base + l16];
            if (l16 < 4)
                yb[base + 16 + l16] = yacc[1][r] * inv64 + xb[base + 16 + l16];
        }
    }
}

extern "C" void kernel_launch(void* const* d_in, const int* in_sizes, int n_in,
                              void* d_out, int out_size, void* d_ws, size_t ws_size,
                              hipStream_t stream) {
    const float* x  = (const float*)d_in[0];
    const float* Wk = (const float*)d_in[1];
    const float* bk = (const float*)d_in[2];
    const float* Wq = (const float*)d_in[3];
    const float* bq = (const float*)d_in[4];
    const float* Wv = (const float*)d_in[5];
    const float* bv = (const float*)d_in[6];
    float* y = (float*)d_out;

    char* ws = (char*)d_ws;
    short* wkT = (short*)ws;                 // tiles 0..6   [112][32] bf16 (bias at c=20)
    short* wqT = (short*)(ws + 7168);        // tiles 7..13  [112][32] bf16
    short* wvT = (short*)(ws + 14336);       // tiles 14..15 [32][32]  bf16 (pre-scaled 2log2e)

    prep<<<14, 256, 0, stream>>>(Wk, bk, Wq, bq, Wv, bv, wkT, wqT, wvT);

    const int B = in_sizes[0] / (T * C);     // 4096
    sa_fused<<<B, NT, 0, stream>>>(x, (const short*)ws, y);
}

// Round 7
// 143.161 us; speedup vs baseline: 1.1904x; 1.1204x over previous
//
#include <hip/hip_runtime.h>
#include <hip/hip_bf16.h>

#define T 128
#define C 20
#define KQ 100
#define NT 256
#define SCALE 0.08838834764831845f   // 1/sqrt(128)
#define K2E   0.12751744f            // SCALE * log2(e)
#define LOG2E 1.4426950408889634f
#define TWOL2E 2.885390081777927f    // 2*log2(e), folded into Wv/bv in prep
#define LDS8 136   // fp8 row stride (bytes): 34 dw == 2 mod 32 -> all accesses <=2-way (free)

typedef float  f32x4  __attribute__((ext_vector_type(4)));
typedef short  bf16x8 __attribute__((ext_vector_type(8)));
typedef unsigned int uint32;

// single-instruction transcendentals via proper builtins (hazard-modeled).
__device__ __forceinline__ float exp2i(float x) { return __builtin_amdgcn_exp2f(x); }
__device__ __forceinline__ float rcpi(float x)  { return __builtin_amdgcn_rcpf(x); }

__device__ __forceinline__ short f2bf(float f) {
    unsigned u = __builtin_bit_cast(unsigned, f);
    unsigned r = (u + 0x7FFFu + ((u >> 16) & 1u)) >> 16;   // RNE
    return (short)r;
}
__device__ __forceinline__ uint32 pk2(float a, float b) {  // v_cvt_pk_bf16_f32
    __hip_bfloat162 h = __float22bfloat162_rn(float2{a, b});
    uint32 r;
    __builtin_memcpy(&r, &h, 4);
    return r;
}
__device__ __forceinline__ int pkfp8x4(float a, float b, float c, float d) {
    int r = __builtin_amdgcn_cvt_pk_fp8_f32(a, b, 0, false);   // bytes 0,1
    r = __builtin_amdgcn_cvt_pk_fp8_f32(c, d, r, true);        // bytes 2,3
    return r;
}
__device__ __forceinline__ unsigned char fp8_1(float a) {
    return (unsigned char)(__builtin_amdgcn_cvt_pk_fp8_f32(a, 0.f, 0, false) & 0xff);
}

// ---- prep: weights -> bf16 A-fragment tiles in d_ws, BIAS FOLDED at c==20 ----
// wAll = 16 tiles x [16 ch][32 c] bf16 (k:0..6, q:7..13, v:14..15).
// Row c=20 of each tile holds the bias (x fragment supplies 1.0 there).
// v weights pre-scaled by 2*log2(e) so tanh needs no input mul in-kernel.
__global__ void prep(const float* __restrict__ Wk, const float* __restrict__ bk,
                     const float* __restrict__ Wq, const float* __restrict__ bq,
                     const float* __restrict__ Wv, const float* __restrict__ bv,
                     short* __restrict__ wkT, short* __restrict__ wqT,
                     short* __restrict__ wvT)
{
    const int t = blockIdx.x * blockDim.x + threadIdx.x;
    if (t < 112 * 32) {
        const int n = t >> 5, c = t & 31;
        float vk = 0.f, vq = 0.f;
        if (n < KQ) {
            if (c < C)       { vk = Wk[c * KQ + n]; vq = Wq[c * KQ + n]; }
            else if (c == C) { vk = bk[n];          vq = bq[n]; }
        }
        wkT[t] = f2bf(vk);
        wqT[t] = f2bf(vq);
        if (t < 32 * 32) {
            const int n2 = t >> 5, c2 = t & 31;
            float vv = 0.f;
            if (n2 < C) {
                if (c2 < C)       vv = Wv[c2 * C + n2] * TWOL2E;
                else if (c2 == C) vv = bv[n2] * TWOL2E;
            }
            wvT[t] = f2bf(vv);
        }
    }
}

// R6 (resubmit — timeout last round): R5 showed VALU 56% + MFMA 15% + ~44%
// stall at the 32-wave cap (8-wave blocks => 4 resident blocks, waves stall
// together at 3 barriers). Restructure for ILP instead of TLP: 256-thread
// blocks, 4 waves, each wave owns TWO tiles (w and w+4). Two independent
// dependency streams per wave fill each other's stalls; score/PV B-operand
// LDS reads shared between streams (1 read feeds 2 MFMAs). LDS unchanged ->
// still 4 blocks/CU; launch_bounds(256,4) -> 128-VGPR budget (acc[2][8]=64
// regs fits).
__global__ __launch_bounds__(NT, 4) void sa_fused(
    const float* __restrict__ x,
    const short* __restrict__ wAll,
    float* __restrict__ y)
{
    __shared__ __align__(16) unsigned char kp8[T * LDS8];   // k fp8 [i][d] -> later 64*P [i][j]
    __shared__ __align__(16) unsigned char q8 [T * LDS8];   // q fp8 [j][d]
    __shared__ __align__(16) unsigned char vT8[32 * LDS8];  // v^T fp8 [dd][pos] (rows 20..31 = 0)

    const int tid  = threadIdx.x;
    const int lane = tid & 63;
    const int w    = __builtin_amdgcn_readfirstlane(tid >> 6);   // 0..3
    const int quad = lane >> 4;
    const int l16  = lane & 15;
    const int b    = blockIdx.x;
    const float* xb = x + (size_t)b * (T * C);

    // ---- issue x global loads FIRST (both row-tiles; latency overlaps pad) ----
    float4 fA[2], fB[2];
    #pragma unroll
    for (int h = 0; h < 2; ++h) {
        const float* xr = xb + ((w + 4 * h) * 16 + l16) * C;
        fA[h] = (float4){0.f, 0.f, 0.f, 0.f};
        fB[h] = (float4){0.f, 0.f, 0.f, 0.f};
        if (quad < 2) {
            fA[h] = *(const float4*)(xr + quad * 8);
            fB[h] = *(const float4*)(xr + quad * 8 + 4);
        } else if (quad == 2) {
            fA[h] = *(const float4*)(xr + 16);
        }
    }

    // ---- zero pad cols 112..127 of kp8/q8 (d-tail read by score K-loop) ----
    if (tid < T) {
        const uint2 z = {0u, 0u};
        *(uint2*)&kp8[tid * LDS8 + 112] = z;
        *(uint2*)&kp8[tid * LDS8 + 120] = z;
        *(uint2*)&q8 [tid * LDS8 + 112] = z;
        *(uint2*)&q8 [tid * LDS8 + 120] = z;
    }

    // ---- x fragments (two i-tiles): A[m=l16][k=quad*8+u] == B[k][n=l16];
    //      c pad 20->32, with c=20 element = 1.0 (bias row multiplier) ----
    bf16x8 xf[2];
    #pragma unroll
    for (int h = 0; h < 2; ++h) {
        uint32 p0 = 0, p1 = 0, p2 = 0, p3 = 0;
        if (quad < 2) {
            p0 = pk2(fA[h].x, fA[h].y); p1 = pk2(fA[h].z, fA[h].w);
            p2 = pk2(fB[h].x, fB[h].y); p3 = pk2(fB[h].z, fB[h].w);
        } else if (quad == 2) {
            p0 = pk2(fA[h].x, fA[h].y); p1 = pk2(fA[h].z, fA[h].w);
            p2 = pk2(1.f, 0.f);                       // c=20 -> 1.0 (bias row)
        }
        uint4 u4; u4.x = p0; u4.y = p1; u4.z = p2; u4.w = p3;
        xf[h] = __builtin_bit_cast(bf16x8, u4);
    }

    // ---- projections (bf16 MFMA): wave w owns i-tiles w and w+4. Weight
    //      fragments loaded once per group, used by both tiles. ----
    #pragma unroll
    for (int grp = 0; grp < 4; ++grp) {
        bf16x8 wfr[4];
        #pragma unroll
        for (int t = 0; t < 4; ++t)
            wfr[t] = *(const bf16x8*)(wAll + ((grp * 4 + t) * 16 + l16) * 32 + quad * 8);
        #pragma unroll
        for (int s = 0; s < 4; ++s) {
            const int tt = grp * 4 + s;
            #pragma unroll
            for (int h = 0; h < 2; ++h) {
                const int row = (w + 4 * h) * 16 + l16;
                const f32x4 cc = __builtin_amdgcn_mfma_f32_16x16x32_bf16(
                    wfr[s], xf[h], (f32x4){0.f, 0.f, 0.f, 0.f}, 0, 0, 0);
                if (tt < 14) {                                    // k or q: ELU -> fp8 b32 write
                    float e[4];
                    #pragma unroll
                    for (int r = 0; r < 4; ++r) {
                        const float z = cc[r];
                        // ELU(z) = median(z, e^z-1, 0): e^z-1 >= z always.
                        e[r] = __builtin_amdgcn_fmed3f(z, exp2i(z * LOG2E) - 1.f, 0.f);
                    }
                    unsigned char* dst = (tt < 7)
                        ? &kp8[row * LDS8 + tt * 16 + quad * 4]
                        : &q8 [row * LDS8 + (tt - 7) * 16 + quad * 4];
                    *(int*)dst = pkfp8x4(e[0], e[1], e[2], e[3]);
                } else {                                          // v: tanh -> vT scatter (b8)
                    #pragma unroll
                    for (int r = 0; r < 4; ++r) {
                        // cc already = 2*log2e*(xWv+bv) via prep pre-scale
                        const float e2 = exp2i(cc[r]);
                        vT8[((tt - 14) * 16 + quad * 4 + r) * LDS8 + row]
                            = fp8_1(fmaf(-2.f, rcpi(e2 + 1.f), 1.f));
                    }
                }
            }
        }
    }
    __syncthreads();

    // ---- scores TRANSPOSED (fp8): S^T = q.k^T. Two j-tiles per wave;
    //      B-operand (k rows) read once, feeds both streams. ----
    f32x4 acc[2][8];
    #pragma unroll
    for (int h = 0; h < 2; ++h)
        #pragma unroll
        for (int nt = 0; nt < 8; ++nt) acc[h][nt] = (f32x4){0.f, 0.f, 0.f, 0.f};
    __builtin_amdgcn_s_setprio(1);
    #pragma unroll
    for (int ks = 0; ks < 4; ++ks) {
        const long a0 = *(const long*)&q8[( w      * 16 + l16) * LDS8 + ks * 32 + quad * 8];
        const long a1 = *(const long*)&q8[((w + 4) * 16 + l16) * LDS8 + ks * 32 + quad * 8];
        #pragma unroll
        for (int nt = 0; nt < 8; ++nt) {
            const long bk8 = *(const long*)&kp8[(nt * 16 + l16) * LDS8 + ks * 32 + quad * 8];
            acc[0][nt] = __builtin_amdgcn_mfma_f32_16x16x32_fp8_fp8(a0, bk8, acc[0][nt], 0, 0, 0);
            acc[1][nt] = __builtin_amdgcn_mfma_f32_16x16x32_fp8_fp8(a1, bk8, acc[1][nt], 0, 0, 0);
        }
    }
    __builtin_amdgcn_s_setprio(0);

    // ---- softmax over i (axis=1), in registers, both j-tiles ----
    float ssum[2][4];
    #pragma unroll
    for (int h = 0; h < 2; ++h) {
        #pragma unroll
        for (int r = 0; r < 4; ++r) ssum[h][r] = 0.f;
        #pragma unroll
        for (int nt = 0; nt < 8; ++nt)
            #pragma unroll
            for (int r = 0; r < 4; ++r) {
                const float e = exp2i(acc[h][nt][r] * K2E);
                acc[h][nt][r] = e;
                ssum[h][r] += e;
            }
        #pragma unroll
        for (int r = 0; r < 4; ++r) {
            float s = ssum[h][r];
            s += __shfl_xor(s, 1); s += __shfl_xor(s, 2);
            s += __shfl_xor(s, 4); s += __shfl_xor(s, 8);
            ssum[h][r] = 64.f * rcpi(s);                          // 64*linv[j]
        }
    }
    __syncthreads();                                              // all score reads of kp8/q8 done

    // ---- write 64*P[i][j] fp8 (b32: 4 consecutive j per thread) both tiles ----
    #pragma unroll
    for (int nt = 0; nt < 8; ++nt) {
        *(int*)&kp8[(nt * 16 + l16) * LDS8 + w * 16 + quad * 4]
            = pkfp8x4(acc[0][nt][0] * ssum[0][0], acc[0][nt][1] * ssum[0][1],
                      acc[0][nt][2] * ssum[0][2], acc[0][nt][3] * ssum[0][3]);
        *(int*)&kp8[(nt * 16 + l16) * LDS8 + (w + 4) * 16 + quad * 4]
            = pkfp8x4(acc[1][nt][0] * ssum[1][0], acc[1][nt][1] * ssum[1][1],
                      acc[1][nt][2] * ssum[1][2], acc[1][nt][3] * ssum[1][3]);
    }
    __syncthreads();

    // ---- PV (fp8): A = 64P rows (two i-tiles), B = v^T (N = 32, shared) ----
    f32x4 yacc[2][2];
    #pragma unroll
    for (int h = 0; h < 2; ++h) {
        yacc[h][0] = (f32x4){0.f, 0.f, 0.f, 0.f};
        yacc[h][1] = (f32x4){0.f, 0.f, 0.f, 0.f};
    }
    __builtin_amdgcn_s_setprio(1);
    #pragma unroll
    for (int ks = 0; ks < 4; ++ks) {
        const long a0 = *(const long*)&kp8[( w      * 16 + l16) * LDS8 + ks * 32 + quad * 8];
        const long a1 = *(const long*)&kp8[((w + 4) * 16 + l16) * LDS8 + ks * 32 + quad * 8];
        #pragma unroll
        for (int nt = 0; nt < 2; ++nt) {
            const long bv8 = *(const long*)&vT8[(nt * 16 + l16) * LDS8 + ks * 32 + quad * 8];
            yacc[0][nt] = __builtin_amdgcn_mfma_f32_16x16x32_fp8_fp8(a0, bv8, yacc[0][nt], 0, 0, 0);
            yacc[1][nt] = __builtin_amdgcn_mfma_f32_16x16x32_fp8_fp8(a1, bv8, yacc[1][nt], 0, 0, 0);
        }
    }
    __builtin_amdgcn_s_setprio(0);

    // ---- epilogue: y = PV/64 + x (direct stores), both i-tiles ----
    {
        float* yb = y + (size_t)b * (T * C);
        const float inv64 = 1.f / 64.f;
        #pragma unroll
        for (int h = 0; h < 2; ++h)
            #pragma unroll
            for (int r = 0; r < 4; ++r) {
                const int row  = (w + 4 * h) * 16 + quad * 4 + r;
                const int base = row * C;
                yb[base + l16] = yacc[h][0][r] * inv64 + xb[base + l16];
                if (l16 < 4)
                    yb[base + 16 + l16] = yacc[h][1][r] * inv64 + xb[base + 16 + l16];
            }
    }
}

extern "C" void kernel_launch(void* const* d_in, const int* in_sizes, int n_in,
                              void* d_out, int out_size, void* d_ws, size_t ws_size,
                              hipStream_t stream) {
    const float* x  = (const float*)d_in[0];
    const float* Wk = (const float*)d_in[1];
    const float* bk = (const float*)d_in[2];
    const float* Wq = (const float*)d_in[3];
    const float* bq = (const float*)d_in[4];
    const float* Wv = (const float*)d_in[5];
    const float* bv = (const float*)d_in[6];
    float* y = (float*)d_out;

    char* ws = (char*)d_ws;
    short* wkT = (short*)ws;                 // tiles 0..6   [112][32] bf16 (bias at c=20)
    short* wqT = (short*)(ws + 7168);        // tiles 7..13  [112][32] bf16
    short* wvT = (short*)(ws + 14336);       // tiles 14..15 [32][32]  bf16 (pre-scaled 2log2e)

    prep<<<14, 256, 0, stream>>>(Wk, bk, Wq, bq, Wv, bv, wkT, wqT, wvT);

    const int B = in_sizes[0] / (T * C);     // 4096
    sa_fused<<<B, NT, 0, stream>>>(x, (const short*)ws, y);
}